// Round 5
// baseline (236.075 us; speedup 1.0000x reference)
//
#include <hip/hip_runtime.h>
#include <stdint.h>

#define D_DIM 4096
#define N_ROWS 8192

typedef __attribute__((ext_vector_type(8))) short bfrag8;
typedef __attribute__((ext_vector_type(4))) float facc4;
typedef unsigned long long u64;

__device__ __forceinline__ uint32_t pack_bf16x2(float lo, float hi) {
    union { float f; uint32_t u; } a, b;
    a.f = lo; b.f = hi;
    return (b.u & 0xFFFF0000u) | (a.u >> 16);   // truncate-to-bf16
}

// ---------------------------------------------------------------------------
// Kernel 0: A fp32 -> bf16, XOR-swizzled per-K-chunk image (verified).
// ---------------------------------------------------------------------------
__global__ void __launch_bounds__(256)
prep_A(const float* __restrict__ A, uint32_t* __restrict__ A_sw) {
    const int S = blockIdx.x * 256 + threadIdx.x;  // 0..65535
    const int c = S >> 10;
    const int s = S & 1023;
    const int n = s >> 3;
    const int g = (s & 7) ^ (n & 7);
    const float* src = A + (size_t)n * D_DIM + c * 64 + g * 8;
    float4 f0 = *(const float4*)(src);
    float4 f1 = *(const float4*)(src + 4);
    uint4 o;
    o.x = pack_bf16x2(f0.x, f0.y);
    o.y = pack_bf16x2(f0.z, f0.w);
    o.z = pack_bf16x2(f1.x, f1.y);
    o.w = pack_bf16x2(f1.z, f1.w);
    *(uint4*)(A_sw + (size_t)S * 4) = o;
}

// ---------------------------------------------------------------------------
// Kernel 1: GEMM + sign-pack, N-SPLIT structure.
// 512 blocks x 512 threads. Block = 16 rows x 128 cols x K=4096.
// 8 waves = 4 col-groups x 2 waves; each wave owns a disjoint 16x16 output
// tile (rows 0..15, cols 32g+16wn+..) -> no cross-wave reduction needed.
// Shared Ls (16x64 bf16, 2.3KB) + shared As chunk (16KB) per iter.
// LDS ~19KB -> 2 blocks/CU, 16 waves/CU.
// Epilogue: ballot -> 16-bit col-slice per row -> LDS gather -> lo^hi fold
// (bit-identical keys to the verified gemm_pack fold).
// (Resubmission x2: rounds 3-4 were broker failures; kernel never ran.)
// ---------------------------------------------------------------------------
__global__ void __launch_bounds__(512)
gemm_pack_n4(const float* __restrict__ L, const uint32_t* __restrict__ A_sw,
             u64* __restrict__ folded) {
    __shared__ ushort Ls[16 * 72];      // 2.25 KB, row stride 72 (verified layout)
    __shared__ uint4  As[1024];         // 16 KB, full 128-col K-chunk (verified swizzle)
    __shared__ ushort sl[8][16];        // 256 B: [16-col slice][row] sign bits

    const int tid  = threadIdx.x;       // 0..511
    const int wave = tid >> 6;          // 0..7
    const int lane = tid & 63;
    const int row0 = blockIdx.x * 16;
    const int c = lane & 15;
    const int q = lane >> 4;
    const int g  = wave >> 1;           // col group 0..3
    const int wn = wave & 1;            // 16-col half within group
    const int ncol = 32 * g + 16 * wn + c;   // global col 0..127

    // Ls staging: threads 0..255, one float4 (4 k-elems) each.
    const int srow = (tid >> 4) & 15;
    const int sf4  = tid & 15;
    const float* lsrc = L + (size_t)(row0 + srow) * D_DIM + sf4 * 4;
    ushort* ldst = &Ls[srow * 72 + sf4 * 4];
    const bool do_ls = (tid < 256);

    facc4 acc = (facc4){0.f, 0.f, 0.f, 0.f};

    for (int kc = 0; kc < D_DIM; kc += 64) {
        const uint32_t* gA = A_sw + (size_t)(kc >> 6) * 4096;
        // As: 1024 uint4 slots = 8 waves x 2 loads x 64 lanes (linear copy).
#pragma unroll
        for (int i = 0; i < 2; i++) {
            const int slot0 = wave * 128 + i * 64;
            __builtin_amdgcn_global_load_lds(
                (const __attribute__((address_space(1))) uint32_t*)(gA + (slot0 + lane) * 4),
                (__attribute__((address_space(3))) uint32_t*)(&As[slot0]),
                16, 0, 0);
        }
        if (do_ls) {
            float4 f = *(const float4*)(lsrc + kc);
            *(uint2*)ldst = make_uint2(pack_bf16x2(f.x, f.y), pack_bf16x2(f.z, f.w));
        }
        __syncthreads();

#pragma unroll
        for (int ks = 0; ks < 2; ks++) {
            bfrag8 a = *(const bfrag8*)&Ls[c * 72 + ks * 32 + q * 8];
            const int gl = ks * 4 + q;
            bfrag8 b = *(const bfrag8*)&As[ncol * 8 + (gl ^ (ncol & 7))];
            acc = __builtin_amdgcn_mfma_f32_16x16x32_bf16(a, b, acc, 0, 0, 0);
        }
        __syncthreads();
    }

    // C/D layout (m89/m91-verified): row = 4q + r, col = c.
    u64 masks[4];
#pragma unroll
    for (int r = 0; r < 4; r++)
        masks[r] = __ballot(acc[r] > 0.0f);

    // slice s = 2g + wn == wave: cols [16s, 16s+16). Lanes 0..15 cover rows.
    if (lane < 16) {
        const int qq = lane >> 2, r = lane & 3;   // row = 4*qq + r = lane
        sl[wave][lane] = (ushort)((masks[r] >> (16 * qq)) & 0xFFFFull);
    }
    __syncthreads();
    if (tid < 16) {
        u64 lo = (u64)sl[0][tid] | ((u64)sl[1][tid] << 16) |
                 ((u64)sl[2][tid] << 32) | ((u64)sl[3][tid] << 48);
        u64 hi = (u64)sl[4][tid] | ((u64)sl[5][tid] << 16) |
                 ((u64)sl[6][tid] << 32) | ((u64)sl[7][tid] << 48);
        folded[row0 + tid] = lo ^ hi;
    }
}

// ---------------------------------------------------------------------------
// Kernel 2: ordered duplicate count, LDS-staged keys, load-balanced rows
// (verified, unchanged).
// ---------------------------------------------------------------------------
__global__ void __launch_bounds__(512)
count_rows(const u64* __restrict__ folded, float* __restrict__ out) {
    __shared__ u64 K[N_ROWS];
    const int tid = threadIdx.x;
    for (int i = tid; i < N_ROWS; i += 512) K[i] = folded[i];
    __syncthreads();

    const int g    = blockIdx.x * 8 + (tid >> 6);   // 0..2047
    const int lane = tid & 63;
    int rows[4];
    u64 my[4];
    int cnt[4] = {0, 0, 0, 0};
#pragma unroll
    for (int r = 0; r < 4; r++) {
        rows[r] = g + 2048 * r;
        my[r] = K[rows[r]];
    }
    const int maxrow = rows[3];
    for (int j = lane; j <= maxrow; j += 64) {
        u64 k = K[j];
#pragma unroll
        for (int r = 0; r < 4; r++)
            cnt[r] += (int)((j <= rows[r]) & (k == my[r]));
    }
#pragma unroll
    for (int r = 0; r < 4; r++) {
        int v = cnt[r];
#pragma unroll
        for (int o = 32; o; o >>= 1) v += __shfl_xor(v, o, 64);
        if (lane == 0) out[rows[r]] = rsqrtf((float)v);
    }
}

extern "C" void kernel_launch(void* const* d_in, const int* in_sizes, int n_in,
                              void* d_out, int out_size, void* d_ws, size_t ws_size,
                              hipStream_t stream) {
    const float* latent = (const float*)d_in[0];   // [128,64,4096] fp32
    const float* A      = (const float*)d_in[1];   // [128,4096] fp32
    float* out          = (float*)d_out;           // [8192] fp32

    uint32_t* A_sw = (uint32_t*)d_ws;                               // 1 MB
    u64* folded = (u64*)((char*)d_ws + (1 << 20));                  // 64 KB

    prep_A<<<256, 256, 0, stream>>>(A, A_sw);
    gemm_pack_n4<<<512, 512, 0, stream>>>(latent, A_sw, folded);
    count_rows<<<256, 512, 0, stream>>>(folded, out);
}